// Round 3
// baseline (1137.270 us; speedup 1.0000x reference)
//
#include <hip/hip_runtime.h>
#include <hip/hip_bf16.h>

#define H_DIM 2048
#define F_DIM 768
#define E_NUM 16
#define T_TOK 4096
#define TOPK  4
#define TK_ROWS (T_TOK * TOPK)

typedef __attribute__((ext_vector_type(8))) short bf16x8;
typedef __attribute__((ext_vector_type(4))) float f32x4;

static __device__ __forceinline__ float bf2f(unsigned short u) {
    return __uint_as_float(((unsigned)u) << 16);
}
static __device__ __forceinline__ unsigned short f2bu(float f) {
    __hip_bfloat16 h = __float2bfloat16(f);
    return *(unsigned short*)&h;
}

// Stage 8 contiguous elements from global (fp32 or bf16) into LDS as bf16.
static __device__ __forceinline__ void stage8(unsigned short* dst, const void* src,
                                              size_t eoff, bool f32) {
    if (f32) {
        const float* s = (const float*)src + eoff;
        float4 a = *(const float4*)s;
        float4 b = *(const float4*)(s + 4);
        __align__(16) unsigned short u[8] = {
            f2bu(a.x), f2bu(a.y), f2bu(a.z), f2bu(a.w),
            f2bu(b.x), f2bu(b.y), f2bu(b.z), f2bu(b.w)};
        *(uint4*)dst = *(const uint4*)u;
    } else {
        *(uint4*)dst = *(const uint4*)((const unsigned short*)src + eoff);
    }
}

// ---------------------------------------------------------------------------
// Dtype probe: fp32 buffers read as ushort have mantissa-junk exponents in the
// even halves; genuine bf16 0.02-scale weights never reach biased exp 135.
// ---------------------------------------------------------------------------
__global__ void probe_kernel(const unsigned short* __restrict__ wr, int* __restrict__ flag) {
    const int tid = threadIdx.x;
    int maxe = 0;
    for (int i = tid; i < 512; i += 64) {
        int e = (wr[i] >> 7) & 0xFF;
        maxe = max(maxe, e);
    }
    for (int off = 32; off > 0; off >>= 1)
        maxe = max(maxe, __shfl_down(maxe, off, 64));
    if (tid == 0) flag[0] = (maxe >= 135) ? 1 : 0;
}

// Convert n elements (fp32->bf16, or copy if already bf16) into dst.
__global__ __launch_bounds__(256)
void convert_kernel(unsigned short* __restrict__ dst, const void* __restrict__ src,
                    const int* __restrict__ dflag, size_t n) {
    const size_t i = ((size_t)blockIdx.x * 256 + threadIdx.x) * 8;
    if (i >= n) return;
    stage8(dst + i, src, i, dflag[0] != 0);
}

// ---------------------------------------------------------------------------
// Router: one block per token. 4 waves; wave w computes experts 4w..4w+3.
// fp32 accumulate from the exact delivered bits (matches np ref either dtype).
// ---------------------------------------------------------------------------
__global__ __launch_bounds__(256)
void router_kernel(const void* __restrict__ xv,
                   const void* __restrict__ wrv,
                   const int* __restrict__ dflag,
                   float* __restrict__ topk_w,
                   int* __restrict__ topk_e,
                   int* __restrict__ counts) {
    const bool f32 = dflag[0] != 0;
    const int t = blockIdx.x;
    __shared__ float xs[H_DIM];
    __shared__ float logits_s[E_NUM];
    const int tid = threadIdx.x;

    if (f32) {
        const float4* xr = (const float4*)((const float*)xv + (size_t)t * H_DIM);
        ((float4*)xs)[tid] = xr[tid];
        ((float4*)xs)[tid + 256] = xr[tid + 256];
    } else {
        const uint4* xr = (const uint4*)((const unsigned short*)xv + (size_t)t * H_DIM);
        uint4 b = xr[tid];
        const unsigned short* bp = (const unsigned short*)&b;
#pragma unroll
        for (int j = 0; j < 8; ++j) xs[tid * 8 + j] = bf2f(bp[j]);
    }
    __syncthreads();

    const int w = tid >> 6;
    const int lane = tid & 63;

    float acc[4] = {0.f, 0.f, 0.f, 0.f};
    for (int i = 0; i < 4; ++i) {
        const int h = i * 512 + lane * 8;
        float xf[8];
#pragma unroll
        for (int j = 0; j < 8; ++j) xf[j] = xs[h + j];
#pragma unroll
        for (int je = 0; je < 4; ++je) {
            const int e = w * 4 + je;
            float wf[8];
            if (f32) {
                const float* wp = (const float*)wrv + (size_t)e * H_DIM + h;
                float4 a = *(const float4*)wp;
                float4 b = *(const float4*)(wp + 4);
                wf[0]=a.x; wf[1]=a.y; wf[2]=a.z; wf[3]=a.w;
                wf[4]=b.x; wf[5]=b.y; wf[6]=b.z; wf[7]=b.w;
            } else {
                uint4 wb = *(const uint4*)((const unsigned short*)wrv + (size_t)e * H_DIM + h);
                const unsigned short* wp = (const unsigned short*)&wb;
#pragma unroll
                for (int j = 0; j < 8; ++j) wf[j] = bf2f(wp[j]);
            }
            float s = 0.f;
#pragma unroll
            for (int j = 0; j < 8; ++j) s += xf[j] * wf[j];
            acc[je] += s;
        }
    }
#pragma unroll
    for (int je = 0; je < 4; ++je) {
        float v = acc[je];
        for (int off = 32; off > 0; off >>= 1) v += __shfl_down(v, off, 64);
        if (lane == 0) logits_s[w * 4 + je] = v;
    }
    __syncthreads();

    if (tid == 0) {
        float l[E_NUM];
#pragma unroll
        for (int i = 0; i < E_NUM; ++i) l[i] = logits_s[i];
        unsigned mask = 0;
        int sel_e[TOPK];
        float sel_v[TOPK];
        for (int k = 0; k < TOPK; ++k) {
            int be = 0; float bv = -1e30f;
            for (int i = 0; i < E_NUM; ++i) {
                if (!(mask & (1u << i)) && l[i] > bv) { bv = l[i]; be = i; }
            }
            mask |= (1u << be);
            sel_e[k] = be; sel_v[k] = bv;
        }
        // renormalized top-k softmax == softmax over the selected logits
        const float m = sel_v[0];
        float ex[TOPK]; float s = 0.f;
        for (int k = 0; k < TOPK; ++k) { ex[k] = __expf(sel_v[k] - m); s += ex[k]; }
        const float inv = 1.f / s;
        for (int k = 0; k < TOPK; ++k) {
            float wgt = ex[k] * inv;
            if (!f32) wgt = bf2f(f2bu(wgt));  // astype(x.dtype): round only in bf16 mode
            topk_w[t * TOPK + k] = wgt;
            topk_e[t * TOPK + k] = sel_e[k];
            atomicAdd(&counts[sel_e[k]], 1);
        }
    }
}

__global__ void scan_kernel(const int* __restrict__ counts, int* __restrict__ offsets) {
    if (threadIdx.x == 0) {
        int s = 0;
        for (int e = 0; e < E_NUM; ++e) { offsets[e] = s; s += counts[e]; }
        offsets[E_NUM] = s;
    }
}

__global__ __launch_bounds__(256)
void scatter_kernel(const int* __restrict__ topk_e, const int* __restrict__ offsets,
                    int* __restrict__ cursors, int* __restrict__ row_token) {
    const int i = blockIdx.x * 256 + threadIdx.x;
    if (i < TK_ROWS) {
        const int e = topk_e[i];
        const int pos = offsets[e] + atomicAdd(&cursors[e], 1);
        row_token[pos] = i;   // encodes token*4 + slot
    }
}

// ---------------------------------------------------------------------------
// Phase A: act[row, f] = silu(x@Wg^T) * (x@Wu^T) for gathered rows of expert e
// 128x128 tile, BK=64, 4 waves of 64x64, mfma 16x16x32 bf16.
// ---------------------------------------------------------------------------
__global__ __launch_bounds__(256, 2)
void gateup_kernel(const void* __restrict__ xv,
                   const void* __restrict__ wgv,
                   const void* __restrict__ wuv,
                   const int* __restrict__ dflag,
                   const int* __restrict__ row_token,
                   const int* __restrict__ counts,
                   const int* __restrict__ offsets,
                   __hip_bfloat16* __restrict__ act_buf) {
    const bool f32 = dflag[0] != 0;
    const int e  = blockIdx.z;
    const int mt = blockIdx.y;
    const int ft = blockIdx.x;
    const int cnt = counts[e];
    if (mt * 128 >= cnt) return;
    const int base = offsets[e];

    __shared__ unsigned short As[128 * 72];
    __shared__ unsigned short Bgs[128 * 72];
    __shared__ unsigned short Bus[128 * 72];
    __shared__ int tok_s[128];

    const int tid = threadIdx.x;
    if (tid < 128) {
        int r = mt * 128 + tid;
        int gr = base + (r < cnt ? r : cnt - 1);
        tok_s[tid] = row_token[gr] >> 2;
    }
    __syncthreads();

    f32x4 accg[4][4], accu[4][4];
#pragma unroll
    for (int mi = 0; mi < 4; ++mi)
#pragma unroll
        for (int ni = 0; ni < 4; ++ni)
#pragma unroll
            for (int r = 0; r < 4; ++r) { accg[mi][ni][r] = 0.f; accu[mi][ni][r] = 0.f; }

    const int wid  = tid >> 6;
    const int lane = tid & 63;
    const int wm = (wid >> 1) * 64;
    const int wn = (wid & 1) * 64;
    const int lr = lane & 15;
    const int lq = lane >> 4;

    const int lrow = tid >> 3;          // 0..31
    const int lcol = (tid & 7) * 8;     // 0..56 (elements)

    const size_t gOff = ((size_t)e * F_DIM + ft * 128) * H_DIM;

    for (int kk = 0; kk < H_DIM / 64; ++kk) {
        const int k0 = kk * 64;
#pragma unroll
        for (int rep = 0; rep < 4; ++rep) {
            const int row = lrow + rep * 32;
            stage8(&As[row * 72 + lcol],  xv,  (size_t)tok_s[row] * H_DIM + k0 + lcol, f32);
            stage8(&Bgs[row * 72 + lcol], wgv, gOff + (size_t)row * H_DIM + k0 + lcol, f32);
            stage8(&Bus[row * 72 + lcol], wuv, gOff + (size_t)row * H_DIM + k0 + lcol, f32);
        }
        __syncthreads();
#pragma unroll
        for (int ks = 0; ks < 2; ++ks) {
            const int kb = ks * 32 + lq * 8;
            bf16x8 a[4], bg[4], bu[4];
#pragma unroll
            for (int mi = 0; mi < 4; ++mi)
                a[mi] = *(const bf16x8*)&As[(wm + mi * 16 + lr) * 72 + kb];
#pragma unroll
            for (int ni = 0; ni < 4; ++ni) {
                bg[ni] = *(const bf16x8*)&Bgs[(wn + ni * 16 + lr) * 72 + kb];
                bu[ni] = *(const bf16x8*)&Bus[(wn + ni * 16 + lr) * 72 + kb];
            }
#pragma unroll
            for (int mi = 0; mi < 4; ++mi)
#pragma unroll
                for (int ni = 0; ni < 4; ++ni) {
                    accg[mi][ni] = __builtin_amdgcn_mfma_f32_16x16x32_bf16(a[mi], bg[ni], accg[mi][ni], 0, 0, 0);
                    accu[mi][ni] = __builtin_amdgcn_mfma_f32_16x16x32_bf16(a[mi], bu[ni], accu[mi][ni], 0, 0, 0);
                }
        }
        __syncthreads();
    }

#pragma unroll
    for (int mi = 0; mi < 4; ++mi) {
#pragma unroll
        for (int r = 0; r < 4; ++r) {
            const int row  = wm + mi * 16 + lq * 4 + r;
            const int grow = mt * 128 + row;
            if (grow < cnt) {
                __hip_bfloat16* dst = act_buf + (size_t)(base + grow) * F_DIM + ft * 128 + wn;
#pragma unroll
                for (int ni = 0; ni < 4; ++ni) {
                    const float g = accg[mi][ni][r];
                    const float u = accu[mi][ni][r];
                    const float s = g / (1.f + __expf(-g));
                    dst[ni * 16 + lr] = __float2bfloat16(s * u);
                }
            }
        }
    }
}

// ---------------------------------------------------------------------------
// Phase B: y = act @ Wd[e]^T, scaled by routing weight, atomicAdd into fp32 OUT
// ---------------------------------------------------------------------------
__global__ __launch_bounds__(256, 2)
void down_kernel(const __hip_bfloat16* __restrict__ act_buf,
                 const void* __restrict__ wdv,
                 const int* __restrict__ dflag,
                 const int* __restrict__ row_token,
                 const int* __restrict__ counts,
                 const int* __restrict__ offsets,
                 const float* __restrict__ topk_w,
                 float* __restrict__ out) {
    const bool f32 = dflag[0] != 0;
    const int e  = blockIdx.z;
    const int mt = blockIdx.y;
    const int ht = blockIdx.x;
    const int cnt = counts[e];
    if (mt * 128 >= cnt) return;
    const int base = offsets[e];

    __shared__ unsigned short As[128 * 72];
    __shared__ unsigned short Bs[128 * 72];
    __shared__ int tok_s[128];
    __shared__ float w_s[128];

    const int tid = threadIdx.x;
    if (tid < 128) {
        int r = mt * 128 + tid;
        int gr = base + (r < cnt ? r : cnt - 1);
        const int t4 = row_token[gr];
        tok_s[tid] = t4 >> 2;
        w_s[tid] = topk_w[t4];
    }
    __syncthreads();

    f32x4 accd[4][4];
#pragma unroll
    for (int mi = 0; mi < 4; ++mi)
#pragma unroll
        for (int ni = 0; ni < 4; ++ni)
#pragma unroll
            for (int r = 0; r < 4; ++r) accd[mi][ni][r] = 0.f;

    const int wid  = tid >> 6;
    const int lane = tid & 63;
    const int wm = (wid >> 1) * 64;
    const int wn = (wid & 1) * 64;
    const int lr = lane & 15;
    const int lq = lane >> 4;

    const int lrow = tid >> 3;
    const int lcol = (tid & 7) * 8;

    const unsigned short* au = (const unsigned short*)act_buf;
    const size_t hOff = ((size_t)e * H_DIM + ht * 128) * F_DIM;

    for (int kk = 0; kk < F_DIM / 64; ++kk) {
        const int k0 = kk * 64;
#pragma unroll
        for (int rep = 0; rep < 4; ++rep) {
            const int row = lrow + rep * 32;
            int ar = mt * 128 + row;
            ar = (ar < cnt) ? ar : (cnt - 1);   // clamp: stay inside this expert's rows
            *(uint4*)&As[row * 72 + lcol] = *(const uint4*)(au + (size_t)(base + ar) * F_DIM + k0 + lcol);
            stage8(&Bs[row * 72 + lcol], wdv, hOff + (size_t)row * F_DIM + k0 + lcol, f32);
        }
        __syncthreads();
#pragma unroll
        for (int ks = 0; ks < 2; ++ks) {
            const int kb = ks * 32 + lq * 8;
            bf16x8 a[4], b[4];
#pragma unroll
            for (int mi = 0; mi < 4; ++mi)
                a[mi] = *(const bf16x8*)&As[(wm + mi * 16 + lr) * 72 + kb];
#pragma unroll
            for (int ni = 0; ni < 4; ++ni)
                b[ni] = *(const bf16x8*)&Bs[(wn + ni * 16 + lr) * 72 + kb];
#pragma unroll
            for (int mi = 0; mi < 4; ++mi)
#pragma unroll
                for (int ni = 0; ni < 4; ++ni)
                    accd[mi][ni] = __builtin_amdgcn_mfma_f32_16x16x32_bf16(a[mi], b[ni], accd[mi][ni], 0, 0, 0);
        }
        __syncthreads();
    }

#pragma unroll
    for (int mi = 0; mi < 4; ++mi) {
#pragma unroll
        for (int r = 0; r < 4; ++r) {
            const int row  = wm + mi * 16 + lq * 4 + r;
            const int grow = mt * 128 + row;
            if (grow < cnt) {
                const float wgt = w_s[row];
                float* dst = out + (size_t)tok_s[row] * H_DIM + ht * 128 + wn;
#pragma unroll
                for (int ni = 0; ni < 4; ++ni)
                    atomicAdd(&dst[ni * 16 + lr], accd[mi][ni][r] * wgt);
            }
        }
    }
}

extern "C" void kernel_launch(void* const* d_in, const int* in_sizes, int n_in,
                              void* d_out, int out_size, void* d_ws, size_t ws_size,
                              hipStream_t stream) {
    const void* x  = d_in[0];
    const void* Wr = d_in[1];
    const void* Wg = d_in[2];
    const void* Wu = d_in[3];
    const void* Wd = d_in[4];
    float* out = (float*)d_out;   // reference output dtype is fp32

    const size_t nX = (size_t)T_TOK * H_DIM;          // 8.39M
    const size_t nW = (size_t)E_NUM * F_DIM * H_DIM;  // 25.2M (Wg/Wu/Wd each)

    char* ws = (char*)d_ws;
    size_t o = 0;
    float* topk_w    = (float*)(ws + o); o += (size_t)TK_ROWS * 4;
    int*   topk_e    = (int*)(ws + o);   o += (size_t)TK_ROWS * 4;
    int*   row_token = (int*)(ws + o);   o += (size_t)TK_ROWS * 4;
    int*   counts    = (int*)(ws + o);   o += 64;
    int*   cursors   = (int*)(ws + o);   o += 64;
    int*   zflag     = (int*)(ws + o);   o += 64;
    int*   dflag     = (int*)(ws + o);   o += 64;
    int*   offsets   = (int*)(ws + o);   o += 128;
    __hip_bfloat16* act_buf = (__hip_bfloat16*)(ws + o); o += (size_t)TK_ROWS * F_DIM * 2; // 25.2 MB
    const size_t baseNeed = o;
    unsigned short* xb  = (unsigned short*)(ws + o); o += nX * 2;
    unsigned short* Wgb = (unsigned short*)(ws + o); o += nW * 2;
    unsigned short* Wub = (unsigned short*)(ws + o); o += nW * 2;
    unsigned short* Wdb = (unsigned short*)(ws + o); o += nW * 2;
    const bool fast = (ws_size >= o);   // need ~194 MB for the bf16-converted path
    (void)baseNeed;

    hipMemsetAsync(out, 0, (size_t)out_size * sizeof(float), stream);
    hipMemsetAsync(counts, 0, 192, stream);   // counts + cursors + zflag

    probe_kernel<<<1, 64, 0, stream>>>((const unsigned short*)Wr, dflag);
    router_kernel<<<T_TOK, 256, 0, stream>>>(x, Wr, dflag, topk_w, topk_e, counts);
    scan_kernel<<<1, 64, 0, stream>>>(counts, offsets);
    scatter_kernel<<<TK_ROWS / 256, 256, 0, stream>>>(topk_e, offsets, cursors, row_token);

    const void* gx = x;  const void* gg = Wg; const void* gu = Wu; const void* gd = Wd;
    const int* gemm_flag = dflag;
    if (fast) {
        convert_kernel<<<(int)(nX / 2048), 256, 0, stream>>>(xb,  x,  dflag, nX);
        convert_kernel<<<(int)(nW / 2048), 256, 0, stream>>>(Wgb, Wg, dflag, nW);
        convert_kernel<<<(int)(nW / 2048), 256, 0, stream>>>(Wub, Wu, dflag, nW);
        convert_kernel<<<(int)(nW / 2048), 256, 0, stream>>>(Wdb, Wd, dflag, nW);
        gx = xb; gg = Wgb; gu = Wub; gd = Wdb;
        gemm_flag = zflag;
    }

    gateup_kernel<<<dim3(F_DIM / 128, 32, E_NUM), 256, 0, stream>>>(
        gx, gg, gu, gemm_flag, row_token, counts, offsets, act_buf);
    down_kernel<<<dim3(H_DIM / 128, 32, E_NUM), 256, 0, stream>>>(
        act_buf, gd, gemm_flag, row_token, counts, offsets, topk_w, out);
}

// Round 4
// 936.911 us; speedup vs baseline: 1.2139x; 1.2139x over previous
//
#include <hip/hip_runtime.h>
#include <hip/hip_bf16.h>

#define H_DIM 2048
#define F_DIM 768
#define E_NUM 16
#define T_TOK 4096
#define TOPK  4
#define TK_ROWS (T_TOK * TOPK)
#define MAX_TILES 160

typedef __attribute__((ext_vector_type(8))) short bf16x8;
typedef __attribute__((ext_vector_type(4))) float f32x4;

static __device__ __forceinline__ float bf2f(unsigned short u) {
    return __uint_as_float(((unsigned)u) << 16);
}
static __device__ __forceinline__ unsigned short f2bu(float f) {
    __hip_bfloat16 h = __float2bfloat16(f);
    return *(unsigned short*)&h;
}

// Direct global->LDS 16B async copy (m97: the 1.69x ladder step).
static __device__ __forceinline__ void gl16(const unsigned short* g, unsigned short* l) {
    __builtin_amdgcn_global_load_lds(
        (__attribute__((address_space(1))) void*)(g),
        (__attribute__((address_space(3))) void*)(l),
        16, 0, 0);
}

// Stage 8 contiguous elements from global (fp32 or bf16) into dst as bf16.
static __device__ __forceinline__ void stage8(unsigned short* dst, const void* src,
                                              size_t eoff, bool f32) {
    if (f32) {
        const float* s = (const float*)src + eoff;
        float4 a = *(const float4*)s;
        float4 b = *(const float4*)(s + 4);
        __align__(16) unsigned short u[8] = {
            f2bu(a.x), f2bu(a.y), f2bu(a.z), f2bu(a.w),
            f2bu(b.x), f2bu(b.y), f2bu(b.z), f2bu(b.w)};
        *(uint4*)dst = *(const uint4*)u;
    } else {
        *(uint4*)dst = *(const uint4*)((const unsigned short*)src + eoff);
    }
}

// ---------------------------------------------------------------------------
// Dtype probe: fp32 buffers read as ushort have mantissa-junk exponents.
// ---------------------------------------------------------------------------
__global__ void probe_kernel(const unsigned short* __restrict__ wr, int* __restrict__ flag) {
    const int tid = threadIdx.x;
    int maxe = 0;
    for (int i = tid; i < 512; i += 64) {
        int e = (wr[i] >> 7) & 0xFF;
        maxe = max(maxe, e);
    }
    for (int off = 32; off > 0; off >>= 1)
        maxe = max(maxe, __shfl_down(maxe, off, 64));
    if (tid == 0) flag[0] = (maxe >= 135) ? 1 : 0;
}

__global__ __launch_bounds__(256)
void convert_kernel(unsigned short* __restrict__ dst, const void* __restrict__ src,
                    const int* __restrict__ dflag, size_t n) {
    const size_t i = ((size_t)blockIdx.x * 256 + threadIdx.x) * 8;
    if (i >= n) return;
    stage8(dst + i, src, i, dflag[0] != 0);
}

// ---------------------------------------------------------------------------
// Router: 8 tokens per block; wave w computes experts 4w..4w+3 for all 8.
// fp32 accumulate from exact delivered bits (matches np top-k either dtype).
// ---------------------------------------------------------------------------
__global__ __launch_bounds__(256, 2)
void router_kernel(const void* __restrict__ xv,
                   const void* __restrict__ wrv,
                   const int* __restrict__ dflag,
                   float* __restrict__ topk_w,
                   int* __restrict__ topk_e,
                   int* __restrict__ counts) {
    const bool f32 = dflag[0] != 0;
    const int t0 = blockIdx.x * 8;
    __shared__ float xs[8][H_DIM];
    __shared__ float logits_s[8][E_NUM];
    const int tid = threadIdx.x;

    if (f32) {
        const float4* src = (const float4*)((const float*)xv + (size_t)t0 * H_DIM);
        float4* dst = (float4*)&xs[0][0];
        for (int i = tid; i < 8 * H_DIM / 4; i += 256) dst[i] = src[i];
    } else {
        const uint4* src = (const uint4*)((const unsigned short*)xv + (size_t)t0 * H_DIM);
        for (int i = tid; i < 8 * H_DIM / 8; i += 256) {
            uint4 b = src[i];
            const unsigned short* bp = (const unsigned short*)&b;
            float* d = &xs[0][0] + (size_t)i * 8;
#pragma unroll
            for (int j = 0; j < 8; ++j) d[j] = bf2f(bp[j]);
        }
    }
    __syncthreads();

    const int w = tid >> 6;
    const int lane = tid & 63;

    float acc[8][4];
#pragma unroll
    for (int t = 0; t < 8; ++t)
#pragma unroll
        for (int je = 0; je < 4; ++je) acc[t][je] = 0.f;

    for (int i = 0; i < 4; ++i) {
        const int h = i * 512 + lane * 8;
#pragma unroll
        for (int je = 0; je < 4; ++je) {
            const int e = w * 4 + je;
            float wf[8];
            if (f32) {
                const float* wp = (const float*)wrv + (size_t)e * H_DIM + h;
                float4 a = *(const float4*)wp;
                float4 b = *(const float4*)(wp + 4);
                wf[0]=a.x; wf[1]=a.y; wf[2]=a.z; wf[3]=a.w;
                wf[4]=b.x; wf[5]=b.y; wf[6]=b.z; wf[7]=b.w;
            } else {
                uint4 wb = *(const uint4*)((const unsigned short*)wrv + (size_t)e * H_DIM + h);
                const unsigned short* wp = (const unsigned short*)&wb;
#pragma unroll
                for (int j = 0; j < 8; ++j) wf[j] = bf2f(wp[j]);
            }
#pragma unroll
            for (int t = 0; t < 8; ++t) {
                const float* xp = &xs[t][h];
                float s = 0.f;
#pragma unroll
                for (int j = 0; j < 8; ++j) s += xp[j] * wf[j];
                acc[t][je] += s;
            }
        }
    }
#pragma unroll
    for (int t = 0; t < 8; ++t)
#pragma unroll
        for (int je = 0; je < 4; ++je) {
            float v = acc[t][je];
            v += __shfl_down(v, 32, 64); v += __shfl_down(v, 16, 64);
            v += __shfl_down(v, 8, 64);  v += __shfl_down(v, 4, 64);
            v += __shfl_down(v, 2, 64);  v += __shfl_down(v, 1, 64);
            if (lane == 0) logits_s[t][w * 4 + je] = v;
        }
    __syncthreads();

    if (tid < 8) {
        const int t = t0 + tid;
        float l[E_NUM];
#pragma unroll
        for (int i = 0; i < E_NUM; ++i) l[i] = logits_s[tid][i];
        unsigned mask = 0;
        int sel_e[TOPK];
        float sel_v[TOPK];
        for (int k = 0; k < TOPK; ++k) {
            int be = 0; float bv = -1e30f;
            for (int i = 0; i < E_NUM; ++i) {
                if (!(mask & (1u << i)) && l[i] > bv) { bv = l[i]; be = i; }
            }
            mask |= (1u << be);
            sel_e[k] = be; sel_v[k] = bv;
        }
        const float m = sel_v[0];
        float ex[TOPK]; float s = 0.f;
        for (int k = 0; k < TOPK; ++k) { ex[k] = __expf(sel_v[k] - m); s += ex[k]; }
        const float inv = 1.f / s;
        for (int k = 0; k < TOPK; ++k) {
            float wgt = ex[k] * inv;
            if (!f32) wgt = bf2f(f2bu(wgt));
            topk_w[t * TOPK + k] = wgt;
            topk_e[t * TOPK + k] = sel_e[k];
            atomicAdd(&counts[sel_e[k]], 1);
        }
    }
}

__global__ void scan_kernel(const int* __restrict__ counts, int* __restrict__ offsets,
                            int* __restrict__ tiles, int* __restrict__ ntiles) {
    if (threadIdx.x == 0) {
        int s = 0, nt = 0;
        for (int e = 0; e < E_NUM; ++e) {
            offsets[e] = s;
            const int c = counts[e];
            s += c;
            for (int mt = 0; mt * 128 < c && nt < MAX_TILES; ++mt)
                tiles[nt++] = (e << 16) | mt;
        }
        offsets[E_NUM] = s;
        ntiles[0] = nt;
    }
}

__global__ __launch_bounds__(256)
void scatter_kernel(const int* __restrict__ topk_e, const int* __restrict__ offsets,
                    int* __restrict__ cursors, int* __restrict__ row_token) {
    const int i = blockIdx.x * 256 + threadIdx.x;
    if (i < TK_ROWS) {
        const int e = topk_e[i];
        const int pos = offsets[e] + atomicAdd(&cursors[e], 1);
        row_token[pos] = i;   // encodes token*4 + slot
    }
}

// ---------------------------------------------------------------------------
// FAST Phase A: bf16-only, global_load_lds staging with XOR-swizzled layout.
// LDS tile 128x64 unpadded; phys col-group = logical-group ^ (row&7).
// ---------------------------------------------------------------------------
__global__ __launch_bounds__(256)
void gateup_fast(const unsigned short* __restrict__ x,
                 const unsigned short* __restrict__ Wg,
                 const unsigned short* __restrict__ Wu,
                 const int* __restrict__ row_token,
                 const int* __restrict__ counts,
                 const int* __restrict__ offsets,
                 const int* __restrict__ tiles,
                 const int* __restrict__ ntiles,
                 __hip_bfloat16* __restrict__ act_buf) {
    const int ti = blockIdx.y;
    if (ti >= ntiles[0]) return;
    const int packed = tiles[ti];
    const int e = packed >> 16, mt = packed & 0xffff;
    const int ft = blockIdx.x;
    const int cnt = counts[e], base = offsets[e];

    __shared__ unsigned short As[128 * 64];
    __shared__ unsigned short Bgs[128 * 64];
    __shared__ unsigned short Bus[128 * 64];
    __shared__ int tok_s[128];

    const int tid = threadIdx.x;
    if (tid < 128) {
        int r = mt * 128 + tid;
        tok_s[tid] = row_token[base + (r < cnt ? r : cnt - 1)] >> 2;
    }
    __syncthreads();

    const int w = tid >> 6;
    const int lane = tid & 63;
    const int subrow = lane >> 3;       // 0..7
    const int sgrp = lane & 7;          // physical 16B group
    const int lgrp = sgrp ^ subrow;     // logical col group (swizzle)

    // Per-j staging geometry (j = 0..3): tile row = (w*4+j)*8 + subrow
    const unsigned short* aptr[4];
    const unsigned short* bgptr[4];
    const unsigned short* buptr[4];
    unsigned short* ldsA[4];
    unsigned short* ldsBg[4];
    unsigned short* ldsBu[4];
    const size_t gOff = ((size_t)e * F_DIM + (size_t)ft * 128) * H_DIM;
#pragma unroll
    for (int j = 0; j < 4; ++j) {
        const int r = (w * 4 + j) * 8 + subrow;
        aptr[j]  = x + (size_t)tok_s[r] * H_DIM + lgrp * 8;
        bgptr[j] = Wg + gOff + (size_t)r * H_DIM + lgrp * 8;
        buptr[j] = Wu + gOff + (size_t)r * H_DIM + lgrp * 8;
        const int lo = r * 64 + sgrp * 8;
        ldsA[j]  = &As[lo];
        ldsBg[j] = &Bgs[lo];
        ldsBu[j] = &Bus[lo];
    }

    f32x4 accg[4][4], accu[4][4];
#pragma unroll
    for (int mi = 0; mi < 4; ++mi)
#pragma unroll
        for (int ni = 0; ni < 4; ++ni)
#pragma unroll
            for (int r = 0; r < 4; ++r) { accg[mi][ni][r] = 0.f; accu[mi][ni][r] = 0.f; }

    const int wm = (w >> 1) * 64;
    const int wn = (w & 1) * 64;
    const int lr = lane & 15;
    const int lq = lane >> 4;
    const int gx = lr & 7;
    // fragment LDS element offsets (ks = 0,1): row*64 + (group ^ (row&7))*8
    const int aoff[2] = { (wm + lr) * 64 + ((lq    ) ^ gx) * 8,
                          (wm + lr) * 64 + ((4 + lq) ^ gx) * 8 };
    const int boff[2] = { (wn + lr) * 64 + ((lq    ) ^ gx) * 8,
                          (wn + lr) * 64 + ((4 + lq) ^ gx) * 8 };

    for (int kk = 0; kk < H_DIM / 64; ++kk) {
        const int k0 = kk * 64;
#pragma unroll
        for (int j = 0; j < 4; ++j) {
            gl16(aptr[j] + k0, ldsA[j]);
            gl16(bgptr[j] + k0, ldsBg[j]);
            gl16(buptr[j] + k0, ldsBu[j]);
        }
        __syncthreads();
#pragma unroll
        for (int ks = 0; ks < 2; ++ks) {
            bf16x8 a[4], bg[4], bu[4];
#pragma unroll
            for (int mi = 0; mi < 4; ++mi)
                a[mi] = *(const bf16x8*)&As[aoff[ks] + mi * 1024];
#pragma unroll
            for (int ni = 0; ni < 4; ++ni) {
                bg[ni] = *(const bf16x8*)&Bgs[boff[ks] + ni * 1024];
                bu[ni] = *(const bf16x8*)&Bus[boff[ks] + ni * 1024];
            }
#pragma unroll
            for (int mi = 0; mi < 4; ++mi)
#pragma unroll
                for (int ni = 0; ni < 4; ++ni) {
                    accg[mi][ni] = __builtin_amdgcn_mfma_f32_16x16x32_bf16(a[mi], bg[ni], accg[mi][ni], 0, 0, 0);
                    accu[mi][ni] = __builtin_amdgcn_mfma_f32_16x16x32_bf16(a[mi], bu[ni], accu[mi][ni], 0, 0, 0);
                }
        }
        __syncthreads();
    }

#pragma unroll
    for (int mi = 0; mi < 4; ++mi) {
#pragma unroll
        for (int r = 0; r < 4; ++r) {
            const int row  = wm + mi * 16 + lq * 4 + r;
            const int grow = mt * 128 + row;
            if (grow < cnt) {
                __hip_bfloat16* dst = act_buf + (size_t)(base + grow) * F_DIM + ft * 128 + wn;
#pragma unroll
                for (int ni = 0; ni < 4; ++ni) {
                    const float g = accg[mi][ni][r];
                    const float u = accu[mi][ni][r];
                    const float s = g / (1.f + __expf(-g));
                    dst[ni * 16 + lr] = __float2bfloat16(s * u);
                }
            }
        }
    }
}

// ---------------------------------------------------------------------------
// FAST Phase B: act @ Wd^T, global_load_lds + swizzle, atomicAdd into fp32 out
// ---------------------------------------------------------------------------
__global__ __launch_bounds__(256)
void down_fast(const unsigned short* __restrict__ act,
               const unsigned short* __restrict__ Wd,
               const int* __restrict__ row_token,
               const int* __restrict__ counts,
               const int* __restrict__ offsets,
               const int* __restrict__ tiles,
               const int* __restrict__ ntiles,
               const float* __restrict__ topk_w,
               float* __restrict__ out) {
    const int ti = blockIdx.y;
    if (ti >= ntiles[0]) return;
    const int packed = tiles[ti];
    const int e = packed >> 16, mt = packed & 0xffff;
    const int ht = blockIdx.x;
    const int cnt = counts[e], base = offsets[e];

    __shared__ unsigned short As[128 * 64];
    __shared__ unsigned short Bs[128 * 64];
    __shared__ int tok_s[128];
    __shared__ float w_s[128];

    const int tid = threadIdx.x;
    if (tid < 128) {
        int r = mt * 128 + tid;
        const int t4 = row_token[base + (r < cnt ? r : cnt - 1)];
        tok_s[tid] = t4 >> 2;
        w_s[tid] = topk_w[t4];
    }
    __syncthreads();

    const int w = tid >> 6;
    const int lane = tid & 63;
    const int subrow = lane >> 3;
    const int sgrp = lane & 7;
    const int lgrp = sgrp ^ subrow;

    const unsigned short* aptr[4];
    const unsigned short* bptr[4];
    unsigned short* ldsA[4];
    unsigned short* ldsB[4];
    const size_t hOff = ((size_t)e * H_DIM + (size_t)ht * 128) * F_DIM;
#pragma unroll
    for (int j = 0; j < 4; ++j) {
        const int r = (w * 4 + j) * 8 + subrow;
        int ar = mt * 128 + r;
        ar = (ar < cnt) ? ar : (cnt - 1);
        aptr[j] = act + (size_t)(base + ar) * F_DIM + lgrp * 8;
        bptr[j] = Wd + hOff + (size_t)r * F_DIM + lgrp * 8;
        const int lo = r * 64 + sgrp * 8;
        ldsA[j] = &As[lo];
        ldsB[j] = &Bs[lo];
    }

    f32x4 accd[4][4];
#pragma unroll
    for (int mi = 0; mi < 4; ++mi)
#pragma unroll
        for (int ni = 0; ni < 4; ++ni)
#pragma unroll
            for (int r = 0; r < 4; ++r) accd[mi][ni][r] = 0.f;

    const int wm = (w >> 1) * 64;
    const int wn = (w & 1) * 64;
    const int lr = lane & 15;
    const int lq = lane >> 4;
    const int gx = lr & 7;
    const int aoff[2] = { (wm + lr) * 64 + ((lq    ) ^ gx) * 8,
                          (wm + lr) * 64 + ((4 + lq) ^ gx) * 8 };
    const int boff[2] = { (wn + lr) * 64 + ((lq    ) ^ gx) * 8,
                          (wn + lr) * 64 + ((4 + lq) ^ gx) * 8 };

    for (int kk = 0; kk < F_DIM / 64; ++kk) {
        const int k0 = kk * 64;
#pragma unroll
        for (int j = 0; j < 4; ++j) {
            gl16(aptr[j] + k0, ldsA[j]);
            gl16(bptr[j] + k0, ldsB[j]);
        }
        __syncthreads();
#pragma unroll
        for (int ks = 0; ks < 2; ++ks) {
            bf16x8 a[4], b[4];
#pragma unroll
            for (int mi = 0; mi < 4; ++mi)
                a[mi] = *(const bf16x8*)&As[aoff[ks] + mi * 1024];
#pragma unroll
            for (int ni = 0; ni < 4; ++ni)
                b[ni] = *(const bf16x8*)&Bs[boff[ks] + ni * 1024];
#pragma unroll
            for (int mi = 0; mi < 4; ++mi)
#pragma unroll
                for (int ni = 0; ni < 4; ++ni)
                    accd[mi][ni] = __builtin_amdgcn_mfma_f32_16x16x32_bf16(a[mi], b[ni], accd[mi][ni], 0, 0, 0);
        }
        __syncthreads();
    }

#pragma unroll
    for (int mi = 0; mi < 4; ++mi) {
#pragma unroll
        for (int r = 0; r < 4; ++r) {
            const int row  = wm + mi * 16 + lq * 4 + r;
            const int grow = mt * 128 + row;
            if (grow < cnt) {
                const float wgt = w_s[row];
                float* dst = out + (size_t)tok_s[row] * H_DIM + ht * 128 + wn;
#pragma unroll
                for (int ni = 0; ni < 4; ++ni)
                    atomicAdd(&dst[ni * 16 + lr], accd[mi][ni][r] * wgt);
            }
        }
    }
}

// ---------------------------------------------------------------------------
// SLOW fallbacks (round-3 proven): dual-dtype staging, full grid.
// ---------------------------------------------------------------------------
__global__ __launch_bounds__(256, 2)
void gateup_slow(const void* __restrict__ xv, const void* __restrict__ wgv,
                 const void* __restrict__ wuv, const int* __restrict__ dflag,
                 const int* __restrict__ row_token, const int* __restrict__ counts,
                 const int* __restrict__ offsets, __hip_bfloat16* __restrict__ act_buf) {
    const bool f32 = dflag[0] != 0;
    const int e = blockIdx.z, mt = blockIdx.y, ft = blockIdx.x;
    const int cnt = counts[e];
    if (mt * 128 >= cnt) return;
    const int base = offsets[e];
    __shared__ unsigned short As[128 * 72];
    __shared__ unsigned short Bgs[128 * 72];
    __shared__ unsigned short Bus[128 * 72];
    __shared__ int tok_s[128];
    const int tid = threadIdx.x;
    if (tid < 128) {
        int r = mt * 128 + tid;
        tok_s[tid] = row_token[base + (r < cnt ? r : cnt - 1)] >> 2;
    }
    __syncthreads();
    f32x4 accg[4][4], accu[4][4];
#pragma unroll
    for (int mi = 0; mi < 4; ++mi)
#pragma unroll
        for (int ni = 0; ni < 4; ++ni)
#pragma unroll
            for (int r = 0; r < 4; ++r) { accg[mi][ni][r] = 0.f; accu[mi][ni][r] = 0.f; }
    const int wid = tid >> 6, lane = tid & 63;
    const int wm = (wid >> 1) * 64, wn = (wid & 1) * 64;
    const int lr = lane & 15, lq = lane >> 4;
    const int lrow = tid >> 3, lcol = (tid & 7) * 8;
    const size_t gOff = ((size_t)e * F_DIM + ft * 128) * H_DIM;
    for (int kk = 0; kk < H_DIM / 64; ++kk) {
        const int k0 = kk * 64;
#pragma unroll
        for (int rep = 0; rep < 4; ++rep) {
            const int row = lrow + rep * 32;
            stage8(&As[row * 72 + lcol],  xv,  (size_t)tok_s[row] * H_DIM + k0 + lcol, f32);
            stage8(&Bgs[row * 72 + lcol], wgv, gOff + (size_t)row * H_DIM + k0 + lcol, f32);
            stage8(&Bus[row * 72 + lcol], wuv, gOff + (size_t)row * H_DIM + k0 + lcol, f32);
        }
        __syncthreads();
#pragma unroll
        for (int ks = 0; ks < 2; ++ks) {
            const int kb = ks * 32 + lq * 8;
            bf16x8 a[4], bg[4], bu[4];
#pragma unroll
            for (int mi = 0; mi < 4; ++mi)
                a[mi] = *(const bf16x8*)&As[(wm + mi * 16 + lr) * 72 + kb];
#pragma unroll
            for (int ni = 0; ni < 4; ++ni) {
                bg[ni] = *(const bf16x8*)&Bgs[(wn + ni * 16 + lr) * 72 + kb];
                bu[ni] = *(const bf16x8*)&Bus[(wn + ni * 16 + lr) * 72 + kb];
            }
#pragma unroll
            for (int mi = 0; mi < 4; ++mi)
#pragma unroll
                for (int ni = 0; ni < 4; ++ni) {
                    accg[mi][ni] = __builtin_amdgcn_mfma_f32_16x16x32_bf16(a[mi], bg[ni], accg[mi][ni], 0, 0, 0);
                    accu[mi][ni] = __builtin_amdgcn_mfma_f32_16x16x32_bf16(a[mi], bu[ni], accu[mi][ni], 0, 0, 0);
                }
        }
        __syncthreads();
    }
#pragma unroll
    for (int mi = 0; mi < 4; ++mi) {
#pragma unroll
        for (int r = 0; r < 4; ++r) {
            const int row = wm + mi * 16 + lq * 4 + r;
            const int grow = mt * 128 + row;
            if (grow < cnt) {
                __hip_bfloat16* dst = act_buf + (size_t)(base + grow) * F_DIM + ft * 128 + wn;
#pragma unroll
                for (int ni = 0; ni < 4; ++ni) {
                    const float g = accg[mi][ni][r];
                    const float u = accu[mi][ni][r];
                    dst[ni * 16 + lr] = __float2bfloat16((g / (1.f + __expf(-g))) * u);
                }
            }
        }
    }
}

__global__ __launch_bounds__(256, 2)
void down_slow(const __hip_bfloat16* __restrict__ act_buf, const void* __restrict__ wdv,
               const int* __restrict__ dflag, const int* __restrict__ row_token,
               const int* __restrict__ counts, const int* __restrict__ offsets,
               const float* __restrict__ topk_w, float* __restrict__ out) {
    const bool f32 = dflag[0] != 0;
    const int e = blockIdx.z, mt = blockIdx.y, ht = blockIdx.x;
    const int cnt = counts[e];
    if (mt * 128 >= cnt) return;
    const int base = offsets[e];
    __shared__ unsigned short As[128 * 72];
    __shared__ unsigned short Bs[128 * 72];
    __shared__ int tok_s[128];
    __shared__ float w_s[128];
    const int tid = threadIdx.x;
    if (tid < 128) {
        int r = mt * 128 + tid;
        const int t4 = row_token[base + (r < cnt ? r : cnt - 1)];
        tok_s[tid] = t4 >> 2;
        w_s[tid] = topk_w[t4];
    }
    __syncthreads();
    f32x4 accd[4][4];
#pragma unroll
    for (int mi = 0; mi < 4; ++mi)
#pragma unroll
        for (int ni = 0; ni < 4; ++ni)
#pragma unroll
            for (int r = 0; r < 4; ++r) accd[mi][ni][r] = 0.f;
    const int wid = tid >> 6, lane = tid & 63;
    const int wm = (wid >> 1) * 64, wn = (wid & 1) * 64;
    const int lr = lane & 15, lq = lane >> 4;
    const int lrow = tid >> 3, lcol = (tid & 7) * 8;
    const unsigned short* au = (const unsigned short*)act_buf;
    const size_t hOff = ((size_t)e * H_DIM + ht * 128) * F_DIM;
    for (int kk = 0; kk < F_DIM / 64; ++kk) {
        const int k0 = kk * 64;
#pragma unroll
        for (int rep = 0; rep < 4; ++rep) {
            const int row = lrow + rep * 32;
            int ar = mt * 128 + row;
            ar = (ar < cnt) ? ar : (cnt - 1);
            *(uint4*)&As[row * 72 + lcol] = *(const uint4*)(au + (size_t)(base + ar) * F_DIM + k0 + lcol);
            stage8(&Bs[row * 72 + lcol], wdv, hOff + (size_t)row * F_DIM + k0 + lcol, f32);
        }
        __syncthreads();
#pragma unroll
        for (int ks = 0; ks < 2; ++ks) {
            const int kb = ks * 32 + lq * 8;
            bf16x8 a[4], b[4];
#pragma unroll
            for (int mi = 0; mi < 4; ++mi)
                a[mi] = *(const bf16x8*)&As[(wm + mi * 16 + lr) * 72 + kb];
#pragma unroll
            for (int ni = 0; ni < 4; ++ni)
                b[ni] = *(const bf16x8*)&Bs[(wn + ni * 16 + lr) * 72 + kb];
#pragma unroll
            for (int mi = 0; mi < 4; ++mi)
#pragma unroll
                for (int ni = 0; ni < 4; ++ni)
                    accd[mi][ni] = __builtin_amdgcn_mfma_f32_16x16x32_bf16(a[mi], b[ni], accd[mi][ni], 0, 0, 0);
        }
        __syncthreads();
    }
#pragma unroll
    for (int mi = 0; mi < 4; ++mi) {
#pragma unroll
        for (int r = 0; r < 4; ++r) {
            const int row = wm + mi * 16 + lq * 4 + r;
            const int grow = mt * 128 + row;
            if (grow < cnt) {
                const float wgt = w_s[row];
                float* dst = out + (size_t)tok_s[row] * H_DIM + ht * 128 + wn;
#pragma unroll
                for (int ni = 0; ni < 4; ++ni)
                    atomicAdd(&dst[ni * 16 + lr], accd[mi][ni][r] * wgt);
            }
        }
    }
}

extern "C" void kernel_launch(void* const* d_in, const int* in_sizes, int n_in,
                              void* d_out, int out_size, void* d_ws, size_t ws_size,
                              hipStream_t stream) {
    const void* x  = d_in[0];
    const void* Wr = d_in[1];
    const void* Wg = d_in[2];
    const void* Wu = d_in[3];
    const void* Wd = d_in[4];
    float* out = (float*)d_out;   // reference output dtype is fp32

    const size_t nX = (size_t)T_TOK * H_DIM;
    const size_t nW = (size_t)E_NUM * F_DIM * H_DIM;

    char* ws = (char*)d_ws;
    size_t o = 0;
    float* topk_w    = (float*)(ws + o); o += (size_t)TK_ROWS * 4;
    int*   topk_e    = (int*)(ws + o);   o += (size_t)TK_ROWS * 4;
    int*   row_token = (int*)(ws + o);   o += (size_t)TK_ROWS * 4;
    int*   counts    = (int*)(ws + o);   o += 64;
    int*   cursors   = (int*)(ws + o);   o += 64;
    int*   zflag     = (int*)(ws + o);   o += 64;
    int*   dflag     = (int*)(ws + o);   o += 64;
    int*   offsets   = (int*)(ws + o);   o += 128;
    int*   ntiles    = (int*)(ws + o);   o += 64;
    int*   tiles     = (int*)(ws + o);   o += MAX_TILES * 4;
    __hip_bfloat16* act_buf = (__hip_bfloat16*)(ws + o); o += (size_t)TK_ROWS * F_DIM * 2;
    unsigned short* xb  = (unsigned short*)(ws + o); o += nX * 2;
    unsigned short* Wgb = (unsigned short*)(ws + o); o += nW * 2;
    unsigned short* Wub = (unsigned short*)(ws + o); o += nW * 2;
    unsigned short* Wdb = (unsigned short*)(ws + o); o += nW * 2;
    const bool fast = (ws_size >= o);
    (void)zflag;

    hipMemsetAsync(out, 0, (size_t)out_size * sizeof(float), stream);
    hipMemsetAsync(counts, 0, 192, stream);   // counts + cursors + zflag

    probe_kernel<<<1, 64, 0, stream>>>((const unsigned short*)Wr, dflag);
    router_kernel<<<T_TOK / 8, 256, 0, stream>>>(x, Wr, dflag, topk_w, topk_e, counts);
    scan_kernel<<<1, 64, 0, stream>>>(counts, offsets, tiles, ntiles);
    scatter_kernel<<<TK_ROWS / 256, 256, 0, stream>>>(topk_e, offsets, cursors, row_token);

    if (fast) {
        convert_kernel<<<(int)(nX / 2048), 256, 0, stream>>>(xb,  x,  dflag, nX);
        convert_kernel<<<(int)(nW / 2048), 256, 0, stream>>>(Wgb, Wg, dflag, nW);
        convert_kernel<<<(int)(nW / 2048), 256, 0, stream>>>(Wub, Wu, dflag, nW);
        convert_kernel<<<(int)(nW / 2048), 256, 0, stream>>>(Wdb, Wd, dflag, nW);
        gateup_fast<<<dim3(F_DIM / 128, MAX_TILES), 256, 0, stream>>>(
            xb, Wgb, Wub, row_token, counts, offsets, tiles, ntiles, act_buf);
        down_fast<<<dim3(H_DIM / 128, MAX_TILES), 256, 0, stream>>>(
            (const unsigned short*)act_buf, Wdb, row_token, counts, offsets,
            tiles, ntiles, topk_w, out);
    } else {
        gateup_slow<<<dim3(F_DIM / 128, 32, E_NUM), 256, 0, stream>>>(
            x, Wg, Wu, dflag, row_token, counts, offsets, act_buf);
        down_slow<<<dim3(H_DIM / 128, 32, E_NUM), 256, 0, stream>>>(
            act_buf, Wd, dflag, row_token, counts, offsets, topk_w, out);
    }
}